// Round 1
// 325.382 us; speedup vs baseline: 1.0265x; 1.0265x over previous
//
#include <hip/hip_runtime.h>
#include <hip/hip_bf16.h>

// ---------------------------------------------------------------------------
// Recommender pipeline, f32 compute.
//  K0 detect : bf16-vs-f32 flag in ws[0]
//  K1 prep   : weights -> f32 in ws; GEMM weights K-PACKED [k/4][128][4]
//  K2 news   : news_e = tanh(elu(title@W1^T+b)@W2^T+b)        [3520,128]
//  K3 gather : X[n] = [ent[node], sum_k(ent[adj]+rel[radj])]  [70400,256]
//              (split out for occupancy/latency-hiding; float4 + shfl idx)
//  K4 anchor : FUSED tanh-GEMM + logits + softmax -> AE
//              X read DIRECTLY from global (wave-uniform 16B loads) instead
//              of LDS staging: frees DS pipe for FMA issue, LDS 62->21 KB
//              doubles occupancy (8 -> 16 waves/CU).
//  K5 mlp    : elu(elu([news_e,AE]@Wm1^T+b)@Wm2^T+b)          [3520,128]
//  K6 score  : user mean + dot                                 [64,5]
// ---------------------------------------------------------------------------

#define B_ 64
#define S_ 5
#define UC_ 50
#define A_ 20
#define NCAND 320
#define NCLK 3200
#define NNEWS 3520
#define NANCH 70400

// ws layout (float indices)
static constexpr long OFF_WNC1P = 64;        // [192][128][4]
static constexpr long OFF_BNC1  = 98368;
static constexpr long OFF_WNC2P = 98496;     // [32][128][4]
static constexpr long OFF_BNC2  = 114880;
static constexpr long OFF_WANCP = 115008;    // [64][128][4]
static constexpr long OFF_BANC  = 147776;
static constexpr long OFF_WAW1P = 147904;    // [32][128][4]
static constexpr long OFF_BAW1  = 164288;
static constexpr long OFF_WAW2  = 164416;    // [128]
static constexpr long OFF_BAW2  = 164544;    // [1]
static constexpr long OFF_WM1P  = 164548;    // [64][128][4]
static constexpr long OFF_BM1   = 197316;
static constexpr long OFF_WM2P  = 197444;    // [32][128][4]
static constexpr long OFF_BM2   = 213828;
static constexpr long OFF_REL   = 213956;    // [100][128]
static constexpr long OFF_AE    = 226756;    // [3520][128]
static constexpr long OFF_NE    = 677316;    // [3520][128]
static constexpr long OFF_MO    = 1127876;   // [3520][128]
static constexpr long OFF_X     = 1578436;   // [70400][256]
// total ~19.6M floats = 78.4 MB

__device__ __forceinline__ float ldf(const void* p, long i, int bf) {
  if (bf) {
    unsigned int u = (unsigned int)((const unsigned short*)p)[i];
    u <<= 16;
    return __uint_as_float(u);
  }
  return ((const float*)p)[i];
}

// 4 consecutive elems starting at i (i % 4 == 0)
__device__ __forceinline__ float4 ldf4(const void* p, long i, int bf) {
  float4 f;
  if (bf) {
    const unsigned short* q = (const unsigned short*)p + i;
    uint2 u = *(const uint2*)q;
    f.x = __uint_as_float(u.x << 16);
    f.y = __uint_as_float(u.x & 0xffff0000u);
    f.z = __uint_as_float(u.y << 16);
    f.w = __uint_as_float(u.y & 0xffff0000u);
  } else {
    f = *(const float4*)((const float*)p + i);
  }
  return f;
}

__device__ __forceinline__ float eluf(float v) { return v > 0.f ? v : expm1f(v); }

// ---- K0: dtype detect -----------------------------------------------------
__global__ void k_detect(const void* ent, int* flag) {
  __shared__ int cnt;
  if (threadIdx.x == 0) cnt = 0;
  __syncthreads();
  unsigned short u = ((const unsigned short*)ent)[threadIdx.x];
  int e = (u >> 7) & 0xFF;
  int ok = (e >= 107 && e <= 146) ? 1 : 0;
  atomicAdd(&cnt, ok);
  __syncthreads();
  if (threadIdx.x == 0) *flag = (cnt >= 200) ? 1 : 0;
}

// ---- K1: convert weights; GEMM weights K-packed ---------------------------
__global__ __launch_bounds__(256) void k_prep(
    const void* s0, const void* s1, const void* s2, const void* s3,
    const void* s4, const void* s5, const void* s6, const void* s7,
    const void* s8, const void* s9, const void* s10, const void* s11,
    const void* s12, const void* s13, const void* s14, float* ws) {
  const int bf = ((const int*)ws)[0];
  const void* srcs[15] = {s0,s1,s2,s3,s4,s5,s6,s7,s8,s9,s10,s11,s12,s13,s14};
  const int R[15] = {128,128,128,128,128,128,128,128,1,  1,  128,128,128,128,100};
  const int C[15] = {768,1,  128,1,  256,1,  128,1,  128,1,  256,1,  128,1,  128};
  const int MD[15]= {2,  0,  2,  0,  2,  0,  2,  0,  0,  0,  2,  0,  2,  0,  0};
  const long OFF[15] = {OFF_WNC1P,OFF_BNC1,OFF_WNC2P,OFF_BNC2,OFF_WANCP,OFF_BANC,
                        OFF_WAW1P,OFF_BAW1,OFF_WAW2,OFF_BAW2,OFF_WM1P,OFF_BM1,
                        OFF_WM2P,OFF_BM2,OFF_REL};
  const long total = 226689;
  for (long idx = (long)blockIdx.x * blockDim.x + threadIdx.x; idx < total;
       idx += (long)gridDim.x * blockDim.x) {
    long rem = idx;
    int s = 0;
    while (rem >= (long)R[s] * C[s]) { rem -= (long)R[s] * C[s]; s++; }
    float v = ldf(srcs[s], rem, bf);
    if (MD[s] == 2) {
      long r = rem / C[s], c = rem - r * C[s];
      ws[OFF[s] + (c >> 2) * 512 + r * 4 + (c & 3)] = v;
    } else {
      ws[OFF[s] + rem] = v;
    }
  }
}

// ---- K2: news title MLP (128 thr, 8 rows, acc[8]) ------------------------
__global__ __launch_bounds__(128) void k_news(const void* titles, const int* cand,
                                              const int* clk, float* ws) {
  const int bf = ((const int*)ws)[0];
  __shared__ __align__(16) float t[8][768];
  __shared__ __align__(16) float h1[8][128];
  int tid = threadIdx.x;
  long r0 = (long)blockIdx.x * 8;
  for (int x = tid * 4; x < 8 * 768; x += 128 * 4) {
    int c = x / 768, k = x - c * 768;
    long i = r0 + c;
    int id = (i < NCAND) ? cand[i] : clk[i - NCAND];
    *(float4*)&t[c][k] = ldf4(titles, (long)id * 768 + k, bf);
  }
  __syncthreads();
  int j = tid;
  const float4* W1 = (const float4*)(ws + OFF_WNC1P);
  float acc[8];
#pragma unroll
  for (int c = 0; c < 8; c++) acc[c] = 0.f;
  for (int k4 = 0; k4 < 192; k4++) {
    float4 w = W1[k4 * 128 + j];
#pragma unroll
    for (int c = 0; c < 8; c++) {
      const float4 xv = *(const float4*)&t[c][k4 * 4];
      acc[c] += w.x * xv.x + w.y * xv.y + w.z * xv.z + w.w * xv.w;
    }
  }
  float b1 = ws[OFF_BNC1 + j];
#pragma unroll
  for (int c = 0; c < 8; c++) h1[c][j] = eluf(acc[c] + b1);
  __syncthreads();
  const float4* W2 = (const float4*)(ws + OFF_WNC2P);
  float a2[8];
#pragma unroll
  for (int c = 0; c < 8; c++) a2[c] = 0.f;
  for (int k4 = 0; k4 < 32; k4++) {
    float4 w = W2[k4 * 128 + j];
#pragma unroll
    for (int c = 0; c < 8; c++) {
      const float4 xv = *(const float4*)&h1[c][k4 * 4];
      a2[c] += w.x * xv.x + w.y * xv.y + w.z * xv.z + w.w * xv.w;
    }
  }
  float b2 = ws[OFF_BNC2 + j];
  float* NE = ws + OFF_NE;
#pragma unroll
  for (int c = 0; c < 8; c++) NE[(r0 + c) * 128 + j] = tanhf(a2[c] + b2);
}

// ---- K3: gather (split, high occupancy, float4 + shfl) --------------------
// 256 thr = 8 groups of 32 lanes; one anchor row per group
__global__ __launch_bounds__(256) void k_gather(const void* ent, const int* canda,
                                                const int* clka, const int* eadj,
                                                const int* radj, float* ws) {
  const int bf = ((const int*)ws)[0];
  int lane = threadIdx.x & 31;
  int grp = threadIdx.x >> 5;
  long n = (long)blockIdx.x * 8 + grp;
  int node = (n < (long)NCAND * A_) ? canda[n] : clka[n - (long)NCAND * A_];
  int idx = 0;
  if (lane < 10) idx = eadj[(long)node * 10 + lane];
  else if (lane < 20) idx = radj[(long)node * 10 + (lane - 10)];
  int an[10], rn[10];
#pragma unroll
  for (int k = 0; k < 10; k++) {
    an[k] = __shfl(idx, k, 32);
    rn[k] = __shfl(idx, k + 10, 32);
  }
  float4 x1 = ldf4(ent, (long)node * 128 + lane * 4, bf);
  const float* relf = ws + OFF_REL;
  float4 acc = {0.f, 0.f, 0.f, 0.f};
#pragma unroll
  for (int k = 0; k < 10; k++) {
    float4 e = ldf4(ent, (long)an[k] * 128 + lane * 4, bf);
    const float4 r = *(const float4*)&relf[(long)rn[k] * 128 + lane * 4];
    acc.x += e.x + r.x;
    acc.y += e.y + r.y;
    acc.z += e.z + r.z;
    acc.w += e.w + r.w;
  }
  float* X = ws + OFF_X;
  *(float4*)&X[n * 256 + lane * 4] = x1;
  *(float4*)&X[n * 256 + 128 + lane * 4] = acc;
}

// ---- K4: FUSED anchor GEMMs + softmax (X read directly from global) -------
// block = 2 news (40 anchors), 256 threads; LDS = H + LG only (~20.6 KB)
// X operand is wave-uniform -> one coalesced 16B request per read; frees the
// DS pipe (stage B previously issued 10 ds_read_b128 broadcasts per k4) and
// lifts occupancy from 2 to 4 blocks/CU.
__global__ __launch_bounds__(256, 4) void k_anchor(float* ws) {
  __shared__ __align__(16) float H[40][128];   // 20 KB
  __shared__ float LG[40];
  int tid = threadIdx.x;
  int lane = tid & 63;
  int wv = __builtin_amdgcn_readfirstlane(tid >> 6);  // wave-uniform row base

  // --- Stage B: H = tanh(X @ Wanc^T + b), 40x128, K=256; X from global ---
  {
    const float4* W4 = (const float4*)(ws + OFF_WANCP);
    const float4* Xr = (const float4*)(ws + OFF_X) +
                       ((long)blockIdx.x * 40 + wv * 10) * 64;  // row-major, 64 f4/row
    float acc[10][2];
#pragma unroll
    for (int r = 0; r < 10; r++) { acc[r][0] = 0.f; acc[r][1] = 0.f; }
    for (int k4 = 0; k4 < 64; k4++) {
      float4 wa = W4[k4 * 128 + lane];
      float4 wb = W4[k4 * 128 + lane + 64];
#pragma unroll
      for (int r = 0; r < 10; r++) {
        const float4 xv = Xr[r * 64 + k4];
        acc[r][0] += wa.x * xv.x + wa.y * xv.y + wa.z * xv.z + wa.w * xv.w;
        acc[r][1] += wb.x * xv.x + wb.y * xv.y + wb.z * xv.z + wb.w * xv.w;
      }
    }
    float ba = ws[OFF_BANC + lane], bb = ws[OFF_BANC + lane + 64];
#pragma unroll
    for (int r = 0; r < 10; r++) {
      H[wv * 10 + r][lane] = tanhf(acc[r][0] + ba);
      H[wv * 10 + r][lane + 64] = tanhf(acc[r][1] + bb);
    }
  }
  __syncthreads();

  // --- Stage C: logits = elu(H@Waw1^T+b)@w2 + b2 ---
  {
    const float4* W4 = (const float4*)(ws + OFF_WAW1P);
    float acc[10][2];
#pragma unroll
    for (int r = 0; r < 10; r++) { acc[r][0] = 0.f; acc[r][1] = 0.f; }
    for (int k4 = 0; k4 < 32; k4++) {
      float4 wa = W4[k4 * 128 + lane];
      float4 wb = W4[k4 * 128 + lane + 64];
#pragma unroll
      for (int r = 0; r < 10; r++) {
        const float4 hv = *(const float4*)&H[wv * 10 + r][k4 * 4];
        acc[r][0] += wa.x * hv.x + wa.y * hv.y + wa.z * hv.z + wa.w * hv.w;
        acc[r][1] += wb.x * hv.x + wb.y * hv.y + wb.z * hv.z + wb.w * hv.w;
      }
    }
    float b1a = ws[OFF_BAW1 + lane], b1b = ws[OFF_BAW1 + lane + 64];
    float w2a = ws[OFF_WAW2 + lane], w2b = ws[OFF_WAW2 + lane + 64];
    float bw2 = ws[OFF_BAW2];
#pragma unroll
    for (int r = 0; r < 10; r++) {
      float part = eluf(acc[r][0] + b1a) * w2a + eluf(acc[r][1] + b1b) * w2b;
#pragma unroll
      for (int o = 32; o > 0; o >>= 1) part += __shfl_down(part, o, 64);
      if (lane == 0) LG[wv * 10 + r] = part + bw2;
    }
  }
  __syncthreads();

  // --- Stage D: softmax over 20 anchors + weighted sum ---
  {
    int d = tid & 127, g = tid >> 7;
    float lg[20];
    float mx = -1e30f;
#pragma unroll
    for (int a = 0; a < 20; a++) { lg[a] = LG[g * 20 + a]; mx = fmaxf(mx, lg[a]); }
    float s = 0.f;
#pragma unroll
    for (int a = 0; a < 20; a++) { lg[a] = expf(lg[a] - mx); s += lg[a]; }
    float inv = 1.0f / s;
    float o = 0.f;
#pragma unroll
    for (int a = 0; a < 20; a++) o += lg[a] * H[g * 20 + a][d];
    float* AE = ws + OFF_AE;
    AE[((long)blockIdx.x * 2 + g) * 128 + d] = o * inv;
  }
}

// ---- K5: final MLP --------------------------------------------------------
__global__ __launch_bounds__(256) void k_mlp(float* ws) {
  __shared__ __align__(16) float xt[16][256];
  __shared__ __align__(16) float h1[16][128];
  int tid = threadIdx.x;
  long r0 = (long)blockIdx.x * 16;
  const float* NE = ws + OFF_NE;
  const float* AE = ws + OFF_AE;
  for (int x = tid; x < 16 * 256; x += 256) {
    int c = x >> 8, k = x & 255;
    xt[c][k] = (k < 128) ? NE[(r0 + c) * 128 + k] : AE[(r0 + c) * 128 + (k - 128)];
  }
  __syncthreads();
  int j = tid & 127, half = tid >> 7;
  const float4* W1 = (const float4*)(ws + OFF_WM1P);
  float acc[8];
#pragma unroll
  for (int c = 0; c < 8; c++) acc[c] = 0.f;
  for (int k4 = 0; k4 < 64; k4++) {
    float4 w = W1[k4 * 128 + j];
#pragma unroll
    for (int c = 0; c < 8; c++) {
      const float4 xv = *(const float4*)&xt[half * 8 + c][k4 * 4];
      acc[c] += w.x * xv.x + w.y * xv.y + w.z * xv.z + w.w * xv.w;
    }
  }
  float b1 = ws[OFF_BM1 + j];
#pragma unroll
  for (int c = 0; c < 8; c++) h1[half * 8 + c][j] = eluf(acc[c] + b1);
  __syncthreads();
  const float4* W2 = (const float4*)(ws + OFF_WM2P);
  float a2[8];
#pragma unroll
  for (int c = 0; c < 8; c++) a2[c] = 0.f;
  for (int k4 = 0; k4 < 32; k4++) {
    float4 w = W2[k4 * 128 + j];
#pragma unroll
    for (int c = 0; c < 8; c++) {
      const float4 xv = *(const float4*)&h1[half * 8 + c][k4 * 4];
      a2[c] += w.x * xv.x + w.y * xv.y + w.z * xv.z + w.w * xv.w;
    }
  }
  float b2 = ws[OFF_BM2 + j];
  float* MO = ws + OFF_MO;
#pragma unroll
  for (int c = 0; c < 8; c++) MO[(r0 + half * 8 + c) * 128 + j] = eluf(a2[c] + b2);
}

// ---- K6: user mean + scores ----------------------------------------------
__global__ __launch_bounds__(128) void k_score(const float* ws, void* out) {
  const int bf = ((const int*)ws)[0];
  int b = blockIdx.x;
  int d = threadIdx.x;
  const float* MO = ws + OFF_MO;
  float u = 0.f;
  for (int t = 0; t < UC_; t++) u += MO[(long)(NCAND + b * UC_ + t) * 128 + d];
  u *= (1.0f / UC_);
  __shared__ float red[2];
  for (int s = 0; s < S_; s++) {
    float p = MO[(long)(b * S_ + s) * 128 + d] * u;
#pragma unroll
    for (int o = 32; o > 0; o >>= 1) p += __shfl_down(p, o, 64);
    if ((d & 63) == 0) red[d >> 6] = p;
    __syncthreads();
    if (d == 0) {
      float v = red[0] + red[1];
      if (bf)
        ((__hip_bfloat16*)out)[b * S_ + s] = __float2bfloat16(v);
      else
        ((float*)out)[b * S_ + s] = v;
    }
    __syncthreads();
  }
}

extern "C" void kernel_launch(void* const* d_in, const int* in_sizes, int n_in,
                              void* d_out, int out_size, void* d_ws, size_t ws_size,
                              hipStream_t stream) {
  (void)in_sizes; (void)n_in; (void)out_size; (void)ws_size;
  const void* titles = d_in[0];
  const void* ent    = d_in[1];
  const void* rel    = d_in[2];
  const void* Wnc1 = d_in[3];  const void* bnc1 = d_in[4];
  const void* Wnc2 = d_in[5];  const void* bnc2 = d_in[6];
  const void* Wanc = d_in[7];  const void* banc = d_in[8];
  const void* Waw1 = d_in[9];  const void* baw1 = d_in[10];
  const void* Waw2 = d_in[11]; const void* baw2 = d_in[12];
  const void* Wm1  = d_in[13]; const void* bm1  = d_in[14];
  const void* Wm2  = d_in[15]; const void* bm2  = d_in[16];
  const int* cand  = (const int*)d_in[17];
  const int* clk   = (const int*)d_in[18];
  const int* canda = (const int*)d_in[19];
  const int* clka  = (const int*)d_in[20];
  const int* eadj  = (const int*)d_in[21];
  const int* radj  = (const int*)d_in[22];
  float* ws = (float*)d_ws;

  k_detect<<<1, 256, 0, stream>>>(ent, (int*)d_ws);
  k_prep<<<256, 256, 0, stream>>>(Wnc1, bnc1, Wnc2, bnc2, Wanc, banc, Waw1, baw1,
                                  Waw2, baw2, Wm1, bm1, Wm2, bm2, rel, ws);
  k_news<<<NNEWS / 8, 128, 0, stream>>>(titles, cand, clk, ws);
  k_gather<<<NANCH / 8, 256, 0, stream>>>(ent, canda, clka, eadj, radj, ws);
  k_anchor<<<NNEWS / 2, 256, 0, stream>>>(ws);
  k_mlp<<<NNEWS / 16, 256, 0, stream>>>(ws);
  k_score<<<B_, 128, 0, stream>>>(ws, d_out);
}